// Round 1
// baseline (249.672 us; speedup 1.0000x reference)
//
#include <hip/hip_runtime.h>
#include <stdint.h>

#define T_TOK 2048
#define HDIM  2048
#define FDIM  1024
#define NEXP  8
#define NSLOT (T_TOK * 2)   // total token-expert slots (exactly 2 per token)

#define BM  128
#define BN  128
#define BK  64
#define BST 72              // B LDS row stride in elems (64 + 8 pad -> 144B, full bank rotation)

typedef unsigned short u16;
typedef __attribute__((ext_vector_type(4))) float f32x4;
typedef __attribute__((ext_vector_type(8))) short bf16x8;
typedef __attribute__((ext_vector_type(8))) unsigned short u16x8;

__device__ __forceinline__ u16 f2bf(float f) {
  uint32_t u = __float_as_uint(f);
  u += 0x7FFFu + ((u >> 16) & 1u);   // RNE
  return (u16)(u >> 16);
}

// ---------------------------------------------------------------------------
// Routing: softmax top-2 over 8 logits; deterministic per-expert token lists
// (token-ascending order via block prefix scan). One block.
// ---------------------------------------------------------------------------
__global__ void route_kernel(const float* __restrict__ logits,
                             int* __restrict__ token_list,   // [NSLOT]
                             float* __restrict__ slot_w,     // [NSLOT]
                             int* __restrict__ counts,       // [NEXP]
                             int* __restrict__ offsets) {    // [NEXP+1]
  const int tid = threadIdx.x;
  __shared__ unsigned char s_eid[T_TOK];
  __shared__ float s_w0[T_TOK];
  __shared__ float s_w1[T_TOK];
  __shared__ int scan[256];
  __shared__ int s_base;

  for (int t = tid; t < T_TOK; t += 256) {
    float l[NEXP];
#pragma unroll
    for (int e = 0; e < NEXP; ++e) l[e] = logits[t * NEXP + e];
    float m = l[0];
#pragma unroll
    for (int e = 1; e < NEXP; ++e) m = fmaxf(m, l[e]);
    float p[NEXP]; float s = 0.f;
#pragma unroll
    for (int e = 0; e < NEXP; ++e) { p[e] = __expf(l[e] - m); s += p[e]; }
    float inv = 1.f / s;
    int i0 = 0; float p0 = p[0];
#pragma unroll
    for (int e = 1; e < NEXP; ++e) if (p[e] > p0) { p0 = p[e]; i0 = e; }
    int i1 = -1; float p1 = -1.f;
#pragma unroll
    for (int e = 0; e < NEXP; ++e) if (e != i0 && p[e] > p1) { p1 = p[e]; i1 = e; }
    s_eid[t] = (unsigned char)(i0 | (i1 << 4));
    s_w0[t] = p0 * inv;
    s_w1[t] = p1 * inv;
  }
  __syncthreads();
  if (tid == 0) s_base = 0;
  __syncthreads();

  for (int e = 0; e < NEXP; ++e) {
    int base0 = s_base;
    if (tid == 0) offsets[e] = base0;
    for (int c = 0; c < T_TOK; c += 256) {
      int t = c + tid;
      int eid = s_eid[t];
      int e0 = eid & 15, e1 = eid >> 4;
      int flag = (e0 == e || e1 == e) ? 1 : 0;
      scan[tid] = flag;
      __syncthreads();
      for (int ofs = 1; ofs < 256; ofs <<= 1) {
        int v = (tid >= ofs) ? scan[tid - ofs] : 0;
        __syncthreads();
        scan[tid] += v;
        __syncthreads();
      }
      int excl = scan[tid] - flag;
      int ctot = scan[255];
      if (flag) {
        token_list[base0 + excl] = t;
        slot_w[base0 + excl] = (e0 == e) ? s_w0[t] : s_w1[t];
      }
      base0 += ctot;
      __syncthreads();
    }
    if (tid == 0) { counts[e] = base0 - offsets[e]; s_base = base0; }
    __syncthreads();
  }
  if (tid == 0) offsets[NEXP] = s_base;
}

// ---------------------------------------------------------------------------
// X fp32 -> bf16
// ---------------------------------------------------------------------------
__global__ void convert_x_kernel(const float4* __restrict__ x, ushort4* __restrict__ xb) {
  int i = blockIdx.x * 256 + threadIdx.x;
  float4 v = x[i];
  ushort4 o;
  o.x = f2bf(v.x); o.y = f2bf(v.y); o.z = f2bf(v.z); o.w = f2bf(v.w);
  xb[i] = o;
}

// ---------------------------------------------------------------------------
// GEMM1: act[slot, f] = silu(x@w1) * (x@w3) * combine_w   (bf16 out)
// A: gathered token rows of Xb (bf16), staged via global_load_lds (16B).
// B: w1/w3 fp32 read strided-coalesced, cvt->bf16, LDS [n][k] (transposed).
// ---------------------------------------------------------------------------
__global__ __launch_bounds__(512)
void gemm1_kernel(const u16* __restrict__ Xb,
                  const float* __restrict__ w1,
                  const float* __restrict__ w3,
                  const int* __restrict__ token_list,
                  const float* __restrict__ slot_w,
                  const int* __restrict__ counts,
                  const int* __restrict__ offsets,
                  u16* __restrict__ act) {
  const int e  = blockIdx.z;
  const int mt = blockIdx.y;
  const int nt = blockIdx.x;
  const int cnt = counts[e];
  if (mt * BM >= cnt) return;
  const int off = offsets[e];
  const int tid  = threadIdx.x;
  const int lane = tid & 63;
  const int wid  = tid >> 6;

  __shared__ u16 A_lds[BM * BK];        // 16 KB, linear [row][k]
  __shared__ u16 B1_lds[BN * BST];      // 18 KB, [n][k] padded
  __shared__ u16 B3_lds[BN * BST];      // 18 KB

  // A staging sources (2 chunks of 1KB per wave; dest = wave-uniform base + lane*16)
  const u16* a_src[2];
#pragma unroll
  for (int r = 0; r < 2; ++r) {
    int chunk = wid * 2 + r;
    int row = chunk * 8 + (lane >> 3);
    int mg = mt * BM + row;
    int mc = (mg < cnt) ? mg : 0;                     // clamp tail rows
    int tok = token_list[off + mc];
    a_src[r] = Xb + (size_t)tok * HDIM + (lane & 7) * 8;
  }

  // B staging: thread covers column n_t, k-range [kq*16, kq*16+16)
  const int n_t = tid & 127;
  const int kq  = tid >> 7;
  const float* p1 = w1 + (size_t)e * HDIM * FDIM + (size_t)(kq * 16) * FDIM + (size_t)nt * BN + n_t;
  const float* p3 = w3 + (size_t)e * HDIM * FDIM + (size_t)(kq * 16) * FDIM + (size_t)nt * BN + n_t;
  u16* bw1 = &B1_lds[n_t * BST + kq * 16];
  u16* bw3 = &B3_lds[n_t * BST + kq * 16];

  const int wm = (wid >> 2) * 64;   // wave row base (0/64)
  const int wn = (wid & 3) * 32;    // wave col base (0/32/64/96)

  f32x4 accg[4][2] = {};
  f32x4 accu[4][2] = {};

#pragma unroll 1
  for (int ks = 0; ks < HDIM; ks += BK) {
#pragma unroll
    for (int r = 0; r < 2; ++r) {
      __builtin_amdgcn_global_load_lds(
          (const __attribute__((address_space(1))) uint32_t*)(a_src[r] + ks),
          (__attribute__((address_space(3))) uint32_t*)&A_lds[(wid * 2 + r) * 512],
          16, 0, 0);
    }
    float v1[16], v3[16];
#pragma unroll
    for (int i = 0; i < 16; ++i) v1[i] = p1[(size_t)i * FDIM];
#pragma unroll
    for (int i = 0; i < 16; ++i) v3[i] = p3[(size_t)i * FDIM];
    p1 += (size_t)BK * FDIM;
    p3 += (size_t)BK * FDIM;
    u16x8 q;
#pragma unroll
    for (int i = 0; i < 8; ++i) q[i] = f2bf(v1[i]);
    *(u16x8*)bw1 = q;
#pragma unroll
    for (int i = 0; i < 8; ++i) q[i] = f2bf(v1[8 + i]);
    *(u16x8*)(bw1 + 8) = q;
#pragma unroll
    for (int i = 0; i < 8; ++i) q[i] = f2bf(v3[i]);
    *(u16x8*)bw3 = q;
#pragma unroll
    for (int i = 0; i < 8; ++i) q[i] = f2bf(v3[8 + i]);
    *(u16x8*)(bw3 + 8) = q;
    __syncthreads();

#pragma unroll
    for (int kk = 0; kk < BK; kk += 32) {
      bf16x8 af[4], bg[2], bu[2];
#pragma unroll
      for (int m = 0; m < 4; ++m)
        af[m] = *(const bf16x8*)&A_lds[(wm + m * 16 + (lane & 15)) * BK + kk + (lane >> 4) * 8];
#pragma unroll
      for (int n = 0; n < 2; ++n) {
        bg[n] = *(const bf16x8*)&B1_lds[(wn + n * 16 + (lane & 15)) * BST + kk + (lane >> 4) * 8];
        bu[n] = *(const bf16x8*)&B3_lds[(wn + n * 16 + (lane & 15)) * BST + kk + (lane >> 4) * 8];
      }
#pragma unroll
      for (int m = 0; m < 4; ++m)
#pragma unroll
        for (int n = 0; n < 2; ++n) {
          accg[m][n] = __builtin_amdgcn_mfma_f32_16x16x32_bf16(af[m], bg[n], accg[m][n], 0, 0, 0);
          accu[m][n] = __builtin_amdgcn_mfma_f32_16x16x32_bf16(af[m], bu[n], accu[m][n], 0, 0, 0);
        }
    }
    __syncthreads();
  }

  // epilogue: silu(g)*u*w -> act bf16.  C/D: col=lane&15, row=(lane>>4)*4+j
  const int rb = mt * BM + wm;
#pragma unroll
  for (int m = 0; m < 4; ++m) {
#pragma unroll
    for (int j = 0; j < 4; ++j) {
      int mg = rb + m * 16 + (lane >> 4) * 4 + j;
      if (mg < cnt) {
        int slot = off + mg;
        float wgt = slot_w[slot];
#pragma unroll
        for (int n = 0; n < 2; ++n) {
          float g = accg[m][n][j];
          float u = accu[m][n][j];
          float sv = g / (1.f + __expf(-g));
          act[(size_t)slot * FDIM + nt * BN + wn + n * 16 + (lane & 15)] = f2bf(sv * u * wgt);
        }
      }
    }
  }
}

// ---------------------------------------------------------------------------
// GEMM2: y[token, h] += act[slot, :] @ w2[e]   (fp32 atomicAdd, 2 addends/elem)
// ---------------------------------------------------------------------------
__global__ __launch_bounds__(512)
void gemm2_kernel(const u16* __restrict__ act,
                  const float* __restrict__ w2,
                  const int* __restrict__ token_list,
                  const int* __restrict__ counts,
                  const int* __restrict__ offsets,
                  float* __restrict__ y) {
  const int e  = blockIdx.z;
  const int mt = blockIdx.y;
  const int nt = blockIdx.x;
  const int cnt = counts[e];
  if (mt * BM >= cnt) return;
  const int off = offsets[e];
  const int tid  = threadIdx.x;
  const int lane = tid & 63;
  const int wid  = tid >> 6;

  __shared__ u16 A_lds[BM * BK];     // 16 KB
  __shared__ u16 B_lds[BN * BST];    // 18 KB

  const u16* a_src[2];
#pragma unroll
  for (int r = 0; r < 2; ++r) {
    int chunk = wid * 2 + r;
    int row = chunk * 8 + (lane >> 3);
    int mg = mt * BM + row;
    int mc = (mg < cnt) ? mg : 0;
    a_src[r] = act + (size_t)(off + mc) * FDIM + (lane & 7) * 8;
  }
  const int n_t = tid & 127;
  const int kq  = tid >> 7;
  const float* p2 = w2 + (size_t)e * FDIM * HDIM + (size_t)(kq * 16) * HDIM + (size_t)nt * BN + n_t;
  u16* bw = &B_lds[n_t * BST + kq * 16];

  const int wm = (wid >> 2) * 64;
  const int wn = (wid & 3) * 32;
  f32x4 acc[4][2] = {};

#pragma unroll 1
  for (int ks = 0; ks < FDIM; ks += BK) {
#pragma unroll
    for (int r = 0; r < 2; ++r) {
      __builtin_amdgcn_global_load_lds(
          (const __attribute__((address_space(1))) uint32_t*)(a_src[r] + ks),
          (__attribute__((address_space(3))) uint32_t*)&A_lds[(wid * 2 + r) * 512],
          16, 0, 0);
    }
    float v[16];
#pragma unroll
    for (int i = 0; i < 16; ++i) v[i] = p2[(size_t)i * HDIM];
    p2 += (size_t)BK * HDIM;
    u16x8 q;
#pragma unroll
    for (int i = 0; i < 8; ++i) q[i] = f2bf(v[i]);
    *(u16x8*)bw = q;
#pragma unroll
    for (int i = 0; i < 8; ++i) q[i] = f2bf(v[8 + i]);
    *(u16x8*)(bw + 8) = q;
    __syncthreads();

#pragma unroll
    for (int kk = 0; kk < BK; kk += 32) {
      bf16x8 af[4], bb[2];
#pragma unroll
      for (int m = 0; m < 4; ++m)
        af[m] = *(const bf16x8*)&A_lds[(wm + m * 16 + (lane & 15)) * BK + kk + (lane >> 4) * 8];
#pragma unroll
      for (int n = 0; n < 2; ++n)
        bb[n] = *(const bf16x8*)&B_lds[(wn + n * 16 + (lane & 15)) * BST + kk + (lane >> 4) * 8];
#pragma unroll
      for (int m = 0; m < 4; ++m)
#pragma unroll
        for (int n = 0; n < 2; ++n)
          acc[m][n] = __builtin_amdgcn_mfma_f32_16x16x32_bf16(af[m], bb[n], acc[m][n], 0, 0, 0);
    }
    __syncthreads();
  }

  const int rb = mt * BM + wm;
#pragma unroll
  for (int m = 0; m < 4; ++m) {
#pragma unroll
    for (int j = 0; j < 4; ++j) {
      int mg = rb + m * 16 + (lane >> 4) * 4 + j;
      if (mg < cnt) {
        int slot = off + mg;
        int tok = token_list[slot];
        float* yp = y + (size_t)tok * HDIM + nt * BN + wn + (lane & 15);
#pragma unroll
        for (int n = 0; n < 2; ++n)
          unsafeAtomicAdd(yp + n * 16, acc[m][n][j]);
      }
    }
  }
}

// ---------------------------------------------------------------------------
extern "C" void kernel_launch(void* const* d_in, const int* in_sizes, int n_in,
                              void* d_out, int out_size, void* d_ws, size_t ws_size,
                              hipStream_t stream) {
  (void)in_sizes; (void)n_in; (void)out_size; (void)ws_size;
  const float* hs     = (const float*)d_in[0];   // (T, H)
  const float* logits = (const float*)d_in[1];   // (T, E)
  const float* w1     = (const float*)d_in[2];   // (E, H, F)
  const float* w3     = (const float*)d_in[3];   // (E, H, F)
  const float* w2     = (const float*)d_in[4];   // (E, F, H)
  float* y = (float*)d_out;

  uint8_t* ws = (uint8_t*)d_ws;
  int*   token_list = (int*)(ws);                         // 16 KB
  float* slot_w     = (float*)(ws + (16 << 10));          // 16 KB
  int*   counts     = (int*)(ws + (32 << 10));            // 32 B
  int*   offsets    = (int*)(ws + (32 << 10) + 256);      // 36 B
  u16*   Xb         = (u16*)(ws + (64 << 10));                              // 8.39 MB
  u16*   act        = (u16*)(ws + (64 << 10) + (size_t)T_TOK * HDIM * 2);   // 8.39 MB

  route_kernel<<<1, 256, 0, stream>>>(logits, token_list, slot_w, counts, offsets);
  convert_x_kernel<<<(T_TOK * HDIM / 4) / 256, 256, 0, stream>>>((const float4*)hs, (ushort4*)Xb);
  hipMemsetAsync(d_out, 0, (size_t)T_TOK * HDIM * sizeof(float), stream);
  gemm1_kernel<<<dim3(FDIM / BN, 16, NEXP), 512, 0, stream>>>(Xb, w1, w3, token_list, slot_w,
                                                              counts, offsets, act);
  gemm2_kernel<<<dim3(HDIM / BN, 16, NEXP), 512, 0, stream>>>(act, w2, token_list, counts,
                                                              offsets, y);
}

// Round 2
// 226.900 us; speedup vs baseline: 1.1004x; 1.1004x over previous
//
#include <hip/hip_runtime.h>
#include <stdint.h>

#define T_TOK 2048
#define HDIM  2048
#define FDIM  1024
#define NEXP  8
#define NSLOT (T_TOK * 2)

#define BM  128
#define BN  128
#define BK  64
#define BST 72              // B LDS row stride (64 + 8 pad -> 144B, bank-rotating)
#define NT_G1 (HDIM / BK)   // 32
#define NT_G2 (FDIM / BK)   // 16

typedef unsigned short u16;
typedef __attribute__((ext_vector_type(4))) float f32x4;
typedef __attribute__((ext_vector_type(8))) short bf16x8;
typedef __attribute__((ext_vector_type(8))) unsigned short u16x8;

__device__ __forceinline__ u16 f2bf(float f) {
  uint32_t u = __float_as_uint(f);
  u += 0x7FFFu + ((u >> 16) & 1u);   // RNE
  return (u16)(u >> 16);
}

__device__ __forceinline__ void glds16(const u16* src, u16* dst) {
  __builtin_amdgcn_global_load_lds(
      (const __attribute__((address_space(1))) uint32_t*)src,
      (__attribute__((address_space(3))) uint32_t*)dst, 16, 0, 0);
}

// ---------------------------------------------------------------------------
// Routing, stage 1: per-token top-2 + per-block histogram -> global counts.
// ---------------------------------------------------------------------------
__global__ void route1_kernel(const float* __restrict__ logits,
                              int* __restrict__ tok_e, float* __restrict__ tok_w,
                              int* __restrict__ counts) {
  __shared__ int lcnt[NEXP];
  const int tid = threadIdx.x;
  const int t = blockIdx.x * 256 + tid;
  if (tid < NEXP) lcnt[tid] = 0;
  __syncthreads();
  float l[NEXP];
#pragma unroll
  for (int e = 0; e < NEXP; ++e) l[e] = logits[t * NEXP + e];
  float m = l[0];
#pragma unroll
  for (int e = 1; e < NEXP; ++e) m = fmaxf(m, l[e]);
  float p[NEXP]; float s = 0.f;
#pragma unroll
  for (int e = 0; e < NEXP; ++e) { p[e] = __expf(l[e] - m); s += p[e]; }
  float inv = 1.f / s;
  int i0 = 0; float p0 = p[0];
#pragma unroll
  for (int e = 1; e < NEXP; ++e) if (p[e] > p0) { p0 = p[e]; i0 = e; }
  int i1 = -1; float p1 = -1.f;
#pragma unroll
  for (int e = 0; e < NEXP; ++e) if (e != i0 && p[e] > p1) { p1 = p[e]; i1 = e; }
  tok_e[t] = i0 | (i1 << 8);
  tok_w[t * 2]     = p0 * inv;
  tok_w[t * 2 + 1] = p1 * inv;
  atomicAdd(&lcnt[i0], 1);
  atomicAdd(&lcnt[i1], 1);
  __syncthreads();
  if (tid < NEXP) atomicAdd(&counts[tid], lcnt[tid]);
}

// Routing, stage 2: scan offsets (8 elems, serial is fine).
__global__ void route2_kernel(const int* __restrict__ counts,
                              int* __restrict__ offsets, int* __restrict__ cursor) {
  if (threadIdx.x == 0) {
    int s = 0;
    for (int e = 0; e < NEXP; ++e) { offsets[e] = s; cursor[e] = s; s += counts[e]; }
    offsets[NEXP] = s;
  }
}

// Routing, stage 3: scatter tokens into grouped slot lists (block-chunked).
// Slot order within an expert is run-varying, but final y is bitwise
// order-invariant: per-row GEMM results are independent, and each y element
// gets exactly 2 commutative fp32 atomic addends.
__global__ void route3_kernel(const int* __restrict__ tok_e, const float* __restrict__ tok_w,
                              int* __restrict__ cursor,
                              int* __restrict__ token_list, float* __restrict__ slot_w) {
  __shared__ int lcnt[NEXP], lbase[NEXP];
  const int tid = threadIdx.x;
  const int t = blockIdx.x * 256 + tid;
  if (tid < NEXP) lcnt[tid] = 0;
  __syncthreads();
  int ee = tok_e[t];
  int e0 = ee & 255, e1 = ee >> 8;
  int li0 = atomicAdd(&lcnt[e0], 1);
  int li1 = atomicAdd(&lcnt[e1], 1);
  __syncthreads();
  if (tid < NEXP) lbase[tid] = atomicAdd(&cursor[tid], lcnt[tid]);
  __syncthreads();
  int s0 = lbase[e0] + li0;
  int s1 = lbase[e1] + li1;
  token_list[s0] = t; slot_w[s0] = tok_w[t * 2];
  token_list[s1] = t; slot_w[s1] = tok_w[t * 2 + 1];
}

// ---------------------------------------------------------------------------
// X fp32 -> bf16
// ---------------------------------------------------------------------------
__global__ void convert_x_kernel(const float4* __restrict__ x, ushort4* __restrict__ xb) {
  int i = blockIdx.x * 256 + threadIdx.x;
  float4 v = x[i];
  ushort4 o;
  o.x = f2bf(v.x); o.y = f2bf(v.y); o.z = f2bf(v.z); o.w = f2bf(v.w);
  xb[i] = o;
}

// ---------------------------------------------------------------------------
// GEMM1: act[slot, f] = silu(x@w1) * (x@w3) * combine_w   (bf16 out)
// Pipelined: loads for tile t+1 issued between the two barriers of tile t,
// drained by the post-MFMA __syncthreads (latency hides under MFMA).
// A tile XOR-swizzled (pre-swizzled glds source + swizzled fragment read).
// ---------------------------------------------------------------------------
__global__ __launch_bounds__(512, 2)
void gemm1_kernel(const u16* __restrict__ Xb,
                  const float* __restrict__ w1,
                  const float* __restrict__ w3,
                  const int* __restrict__ token_list,
                  const float* __restrict__ slot_w,
                  const int* __restrict__ counts,
                  const int* __restrict__ offsets,
                  u16* __restrict__ act) {
  const int e  = blockIdx.z;
  const int mt = blockIdx.y;
  const int nt = blockIdx.x;
  const int cnt = counts[e];
  if (mt * BM >= cnt) return;
  const int off = offsets[e];
  const int tid  = threadIdx.x;
  const int lane = tid & 63;
  const int wid  = tid >> 6;

  __shared__ u16 A_lds[2][BM * BK];     // 32 KB double-buffered
  __shared__ u16 B1_lds[BN * BST];      // 18 KB
  __shared__ u16 B3_lds[BN * BST];      // 18 KB

  // A staging gather sources; source column granule pre-swizzled: granule
  // g at LDS row r holds global granule g ^ (r&7).
  const u16* a_src[2];
#pragma unroll
  for (int r = 0; r < 2; ++r) {
    int chunk = wid * 2 + r;
    int rowc = lane >> 3;                    // row within 8-row chunk == row&7
    int mg = mt * BM + chunk * 8 + rowc;
    int mc = (mg < cnt) ? mg : 0;
    int tok = token_list[off + mc];
    a_src[r] = Xb + (size_t)tok * HDIM + (((lane & 7) ^ rowc) * 8);
  }

  const int n_t = tid & 127;
  const int kq  = tid >> 7;
  const float* p1 = w1 + (size_t)e * HDIM * FDIM + (size_t)(kq * 16) * FDIM + (size_t)nt * BN + n_t;
  const float* p3 = w3 + (size_t)e * HDIM * FDIM + (size_t)(kq * 16) * FDIM + (size_t)nt * BN + n_t;
  u16* bw1 = &B1_lds[n_t * BST + kq * 16];
  u16* bw3 = &B3_lds[n_t * BST + kq * 16];

  const int wm = (wid >> 2) * 64;
  const int wn = (wid & 3) * 32;

  f32x4 accg[4][2] = {};
  f32x4 accu[4][2] = {};

  float v1[16], v3[16];
  // prologue: issue tile-0 A glds + B reg loads
#pragma unroll
  for (int r = 0; r < 2; ++r)
    glds16(a_src[r], &A_lds[0][(wid * 2 + r) * 512]);
#pragma unroll
  for (int i = 0; i < 16; ++i) v1[i] = p1[(size_t)i * FDIM];
#pragma unroll
  for (int i = 0; i < 16; ++i) v3[i] = p3[(size_t)i * FDIM];
  p1 += (size_t)BK * FDIM;
  p3 += (size_t)BK * FDIM;

#pragma unroll 1
  for (int t = 0; t < NT_G1; ++t) {
    // write B(t) regs -> LDS
    u16x8 q;
#pragma unroll
    for (int i = 0; i < 8; ++i) q[i] = f2bf(v1[i]);
    *(u16x8*)bw1 = q;
#pragma unroll
    for (int i = 0; i < 8; ++i) q[i] = f2bf(v1[8 + i]);
    *(u16x8*)(bw1 + 8) = q;
#pragma unroll
    for (int i = 0; i < 8; ++i) q[i] = f2bf(v3[i]);
    *(u16x8*)bw3 = q;
#pragma unroll
    for (int i = 0; i < 8; ++i) q[i] = f2bf(v3[8 + i]);
    *(u16x8*)(bw3 + 8) = q;
    __syncthreads();   // tile t fully in LDS (A glds drained here or earlier)

    if (t + 1 < NT_G1) {             // issue tile t+1 loads; drained post-MFMA
      const int ks = (t + 1) * BK;
#pragma unroll
      for (int r = 0; r < 2; ++r)
        glds16(a_src[r] + ks, &A_lds[(t + 1) & 1][(wid * 2 + r) * 512]);
#pragma unroll
      for (int i = 0; i < 16; ++i) v1[i] = p1[(size_t)i * FDIM];
#pragma unroll
      for (int i = 0; i < 16; ++i) v3[i] = p3[(size_t)i * FDIM];
      p1 += (size_t)BK * FDIM;
      p3 += (size_t)BK * FDIM;
    }

    const u16* Ab = A_lds[t & 1];
#pragma unroll
    for (int kk = 0; kk < BK; kk += 32) {
      bf16x8 af[4], bg[2], bu[2];
#pragma unroll
      for (int m = 0; m < 4; ++m) {
        int R = wm + m * 16 + (lane & 15);
        af[m] = *(const bf16x8*)&Ab[R * BK + ((((kk >> 3) + (lane >> 4)) ^ (R & 7)) * 8)];
      }
#pragma unroll
      for (int n = 0; n < 2; ++n) {
        bg[n] = *(const bf16x8*)&B1_lds[(wn + n * 16 + (lane & 15)) * BST + kk + (lane >> 4) * 8];
        bu[n] = *(const bf16x8*)&B3_lds[(wn + n * 16 + (lane & 15)) * BST + kk + (lane >> 4) * 8];
      }
#pragma unroll
      for (int m = 0; m < 4; ++m)
#pragma unroll
        for (int n = 0; n < 2; ++n) {
          accg[m][n] = __builtin_amdgcn_mfma_f32_16x16x32_bf16(af[m], bg[n], accg[m][n], 0, 0, 0);
          accu[m][n] = __builtin_amdgcn_mfma_f32_16x16x32_bf16(af[m], bu[n], accu[m][n], 0, 0, 0);
        }
    }
    __syncthreads();   // MFMA(t) done; also drains tile t+1 loads (hidden)
  }

  // epilogue: silu(g)*u*w -> act bf16.  C/D: col=lane&15, row=(lane>>4)*4+j
  const int rb = mt * BM + wm;
#pragma unroll
  for (int m = 0; m < 4; ++m) {
#pragma unroll
    for (int j = 0; j < 4; ++j) {
      int mg = rb + m * 16 + (lane >> 4) * 4 + j;
      if (mg < cnt) {
        int slot = off + mg;
        float wgt = slot_w[slot];
#pragma unroll
        for (int n = 0; n < 2; ++n) {
          float g = accg[m][n][j];
          float u = accu[m][n][j];
          float sv = g / (1.f + __expf(-g));
          act[(size_t)slot * FDIM + nt * BN + wn + n * 16 + (lane & 15)] = f2bf(sv * u * wgt);
        }
      }
    }
  }
}

// ---------------------------------------------------------------------------
// GEMM2: y[token, h] += act[slot, :] @ w2[e]   (fp32 atomicAdd, 2 addends/elem)
// Same pipelined structure as gemm1.
// ---------------------------------------------------------------------------
__global__ __launch_bounds__(512, 2)
void gemm2_kernel(const u16* __restrict__ act,
                  const float* __restrict__ w2,
                  const int* __restrict__ token_list,
                  const int* __restrict__ counts,
                  const int* __restrict__ offsets,
                  float* __restrict__ y) {
  const int e  = blockIdx.z;
  const int mt = blockIdx.y;
  const int nt = blockIdx.x;
  const int cnt = counts[e];
  if (mt * BM >= cnt) return;
  const int off = offsets[e];
  const int tid  = threadIdx.x;
  const int lane = tid & 63;
  const int wid  = tid >> 6;

  __shared__ u16 A_lds[2][BM * BK];   // 32 KB
  __shared__ u16 B_lds[BN * BST];     // 18 KB

  const u16* a_src[2];
#pragma unroll
  for (int r = 0; r < 2; ++r) {
    int chunk = wid * 2 + r;
    int rowc = lane >> 3;
    int mg = mt * BM + chunk * 8 + rowc;
    int mc = (mg < cnt) ? mg : 0;
    a_src[r] = act + (size_t)(off + mc) * FDIM + (((lane & 7) ^ rowc) * 8);
  }
  const int n_t = tid & 127;
  const int kq  = tid >> 7;
  const float* p2 = w2 + (size_t)e * FDIM * HDIM + (size_t)(kq * 16) * HDIM + (size_t)nt * BN + n_t;
  u16* bw = &B_lds[n_t * BST + kq * 16];

  const int wm = (wid >> 2) * 64;
  const int wn = (wid & 3) * 32;
  f32x4 acc[4][2] = {};

  float v[16];
#pragma unroll
  for (int r = 0; r < 2; ++r)
    glds16(a_src[r], &A_lds[0][(wid * 2 + r) * 512]);
#pragma unroll
  for (int i = 0; i < 16; ++i) v[i] = p2[(size_t)i * HDIM];
  p2 += (size_t)BK * HDIM;

#pragma unroll 1
  for (int t = 0; t < NT_G2; ++t) {
    u16x8 q;
#pragma unroll
    for (int i = 0; i < 8; ++i) q[i] = f2bf(v[i]);
    *(u16x8*)bw = q;
#pragma unroll
    for (int i = 0; i < 8; ++i) q[i] = f2bf(v[8 + i]);
    *(u16x8*)(bw + 8) = q;
    __syncthreads();

    if (t + 1 < NT_G2) {
      const int ks = (t + 1) * BK;
#pragma unroll
      for (int r = 0; r < 2; ++r)
        glds16(a_src[r] + ks, &A_lds[(t + 1) & 1][(wid * 2 + r) * 512]);
#pragma unroll
      for (int i = 0; i < 16; ++i) v[i] = p2[(size_t)i * HDIM];
      p2 += (size_t)BK * HDIM;
    }

    const u16* Ab = A_lds[t & 1];
#pragma unroll
    for (int kk = 0; kk < BK; kk += 32) {
      bf16x8 af[4], bb[2];
#pragma unroll
      for (int m = 0; m < 4; ++m) {
        int R = wm + m * 16 + (lane & 15);
        af[m] = *(const bf16x8*)&Ab[R * BK + ((((kk >> 3) + (lane >> 4)) ^ (R & 7)) * 8)];
      }
#pragma unroll
      for (int n = 0; n < 2; ++n)
        bb[n] = *(const bf16x8*)&B_lds[(wn + n * 16 + (lane & 15)) * BST + kk + (lane >> 4) * 8];
#pragma unroll
      for (int m = 0; m < 4; ++m)
#pragma unroll
        for (int n = 0; n < 2; ++n)
          acc[m][n] = __builtin_amdgcn_mfma_f32_16x16x32_bf16(af[m], bb[n], acc[m][n], 0, 0, 0);
    }
    __syncthreads();
  }

  const int rb = mt * BM + wm;
#pragma unroll
  for (int m = 0; m < 4; ++m) {
#pragma unroll
    for (int j = 0; j < 4; ++j) {
      int mg = rb + m * 16 + (lane >> 4) * 4 + j;
      if (mg < cnt) {
        int slot = off + mg;
        int tok = token_list[slot];
        float* yp = y + (size_t)tok * HDIM + nt * BN + wn + (lane & 15);
#pragma unroll
        for (int n = 0; n < 2; ++n)
          unsafeAtomicAdd(yp + n * 16, acc[m][n][j]);
      }
    }
  }
}

// ---------------------------------------------------------------------------
extern "C" void kernel_launch(void* const* d_in, const int* in_sizes, int n_in,
                              void* d_out, int out_size, void* d_ws, size_t ws_size,
                              hipStream_t stream) {
  (void)in_sizes; (void)n_in; (void)out_size; (void)ws_size;
  const float* hs     = (const float*)d_in[0];   // (T, H)
  const float* logits = (const float*)d_in[1];   // (T, E)
  const float* w1     = (const float*)d_in[2];   // (E, H, F)
  const float* w3     = (const float*)d_in[3];   // (E, H, F)
  const float* w2     = (const float*)d_in[4];   // (E, F, H)
  float* y = (float*)d_out;

  uint8_t* ws = (uint8_t*)d_ws;
  int*   token_list = (int*)(ws);                         // 16 KB
  float* slot_w     = (float*)(ws + (16 << 10));          // 16 KB
  int*   counts     = (int*)(ws + (32 << 10));            // 32 B
  int*   offsets    = (int*)(ws + (32 << 10) + 128);      // 36 B
  int*   cursor     = (int*)(ws + (32 << 10) + 256);      // 32 B
  int*   tok_e      = (int*)(ws + (33 << 10));            // 8 KB
  float* tok_w      = (float*)(ws + (42 << 10));          // 16 KB
  u16*   Xb         = (u16*)(ws + (64 << 10));                              // 8.39 MB
  u16*   act        = (u16*)(ws + (64 << 10) + (size_t)T_TOK * HDIM * 2);   // 8.39 MB

  hipMemsetAsync(counts, 0, NEXP * sizeof(int), stream);
  route1_kernel<<<T_TOK / 256, 256, 0, stream>>>(logits, tok_e, tok_w, counts);
  route2_kernel<<<1, 64, 0, stream>>>(counts, offsets, cursor);
  route3_kernel<<<T_TOK / 256, 256, 0, stream>>>(tok_e, tok_w, cursor, token_list, slot_w);
  convert_x_kernel<<<(T_TOK * HDIM / 4) / 256, 256, 0, stream>>>((const float4*)hs, (ushort4*)Xb);
  hipMemsetAsync(d_out, 0, (size_t)T_TOK * HDIM * sizeof(float), stream);
  gemm1_kernel<<<dim3(FDIM / BN, 16, NEXP), 512, 0, stream>>>(Xb, w1, w3, token_list, slot_w,
                                                              counts, offsets, act);
  gemm2_kernel<<<dim3(HDIM / BN, 16, NEXP), 512, 0, stream>>>(act, w2, token_list, counts,
                                                              offsets, y);
}

// Round 3
// 192.119 us; speedup vs baseline: 1.2996x; 1.1810x over previous
//
#include <hip/hip_runtime.h>
#include <stdint.h>

#define T_TOK 2048
#define HDIM  2048
#define FDIM  1024
#define NEXP  8

#define BM   128
#define BN   64
#define BK   32
#define NTHR 256
#define MT_MAX (T_TOK / BM)      // 16
#define NT1 (FDIM / BN)          // 16
#define NT2 (HDIM / BN)          // 32
#define NK1 (HDIM / BK)          // 64
#define NK2 (FDIM / BK)          // 32
#define GRID1 (NEXP * NT1 * MT_MAX)   // 2048
#define GRID2 (NEXP * NT2 * MT_MAX)   // 4096

typedef unsigned short u16;
typedef __attribute__((ext_vector_type(4))) float f32x4;
typedef __attribute__((ext_vector_type(8))) short bf16x8;
typedef __attribute__((ext_vector_type(8))) unsigned short u16x8;

__device__ __forceinline__ u16 f2bf(float f) {
  uint32_t u = __float_as_uint(f);
  u += 0x7FFFu + ((u >> 16) & 1u);   // RNE
  return (u16)(u >> 16);
}

__device__ __forceinline__ void glds16(const u16* src, u16* dst) {
  __builtin_amdgcn_global_load_lds(
      (const __attribute__((address_space(1))) uint32_t*)src,
      (__attribute__((address_space(3))) uint32_t*)dst, 16, 0, 0);
}

// ---------------------------------------------------------------------------
// Routing (3 tiny kernels). Slot order within an expert is run-varying, but
// y is order-invariant: per-row GEMM math is slot-position-independent and
// each y element receives exactly 2 commutative fp32 atomic addends.
// ---------------------------------------------------------------------------
__global__ void route1_kernel(const float* __restrict__ logits,
                              int* __restrict__ tok_e, float* __restrict__ tok_w,
                              int* __restrict__ counts) {
  __shared__ int lcnt[NEXP];
  const int tid = threadIdx.x;
  const int t = blockIdx.x * 256 + tid;
  if (tid < NEXP) lcnt[tid] = 0;
  __syncthreads();
  float l[NEXP];
#pragma unroll
  for (int e = 0; e < NEXP; ++e) l[e] = logits[t * NEXP + e];
  float m = l[0];
#pragma unroll
  for (int e = 1; e < NEXP; ++e) m = fmaxf(m, l[e]);
  float p[NEXP]; float s = 0.f;
#pragma unroll
  for (int e = 0; e < NEXP; ++e) { p[e] = __expf(l[e] - m); s += p[e]; }
  float inv = 1.f / s;
  int i0 = 0; float p0 = p[0];
#pragma unroll
  for (int e = 1; e < NEXP; ++e) if (p[e] > p0) { p0 = p[e]; i0 = e; }
  int i1 = -1; float p1 = -1.f;
#pragma unroll
  for (int e = 0; e < NEXP; ++e) if (e != i0 && p[e] > p1) { p1 = p[e]; i1 = e; }
  tok_e[t] = i0 | (i1 << 8);
  tok_w[t * 2]     = p0 * inv;
  tok_w[t * 2 + 1] = p1 * inv;
  atomicAdd(&lcnt[i0], 1);
  atomicAdd(&lcnt[i1], 1);
  __syncthreads();
  if (tid < NEXP) atomicAdd(&counts[tid], lcnt[tid]);
}

__global__ void route2_kernel(const int* __restrict__ counts,
                              int* __restrict__ offsets, int* __restrict__ cursor) {
  if (threadIdx.x == 0) {
    int s = 0;
    for (int e = 0; e < NEXP; ++e) { offsets[e] = s; cursor[e] = s; s += counts[e]; }
    offsets[NEXP] = s;
  }
}

__global__ void route3_kernel(const int* __restrict__ tok_e, const float* __restrict__ tok_w,
                              int* __restrict__ cursor,
                              int* __restrict__ token_list, float* __restrict__ slot_w) {
  __shared__ int lcnt[NEXP], lbase[NEXP];
  const int tid = threadIdx.x;
  const int t = blockIdx.x * 256 + tid;
  if (tid < NEXP) lcnt[tid] = 0;
  __syncthreads();
  int ee = tok_e[t];
  int e0 = ee & 255, e1 = ee >> 8;
  int li0 = atomicAdd(&lcnt[e0], 1);
  int li1 = atomicAdd(&lcnt[e1], 1);
  __syncthreads();
  if (tid < NEXP) lbase[tid] = atomicAdd(&cursor[tid], lcnt[tid]);
  __syncthreads();
  int s0 = lbase[e0] + li0;
  int s1 = lbase[e1] + li1;
  token_list[s0] = t; slot_w[s0] = tok_w[t * 2];
  token_list[s1] = t; slot_w[s1] = tok_w[t * 2 + 1];
}

__global__ void convert_x_kernel(const float4* __restrict__ x, ushort4* __restrict__ xb) {
  int i = blockIdx.x * 256 + threadIdx.x;
  float4 v = x[i];
  ushort4 o;
  o.x = f2bf(v.x); o.y = f2bf(v.y); o.z = f2bf(v.z); o.w = f2bf(v.w);
  xb[i] = o;
}

// ---------------------------------------------------------------------------
// GEMM1: act[slot,f] = silu(x@w1)*(x@w3)*combine_w  (bf16 out)
// 256 thr, BM=128 BN=64 BK=32; A via glds16 (XOR-swizzled src), B via 8+8
// fp32 reg loads -> cvt -> LDS. mt-fastest flat grid + chunked XCD swizzle.
// ---------------------------------------------------------------------------
__global__ __launch_bounds__(NTHR, 3)
void gemm1_kernel(const u16* __restrict__ Xb,
                  const float* __restrict__ w1,
                  const float* __restrict__ w3,
                  const int* __restrict__ token_list,
                  const float* __restrict__ slot_w,
                  const int* __restrict__ counts,
                  const int* __restrict__ offsets,
                  u16* __restrict__ act) {
  const int bid  = blockIdx.x;
  const int orig = (bid & 7) * (GRID1 / 8) + (bid >> 3);
  const int e  = orig >> 8;           // / (NT1*MT_MAX)
  const int nt = (orig >> 4) & 15;
  const int mt = orig & 15;
  const int cnt = counts[e];
  if (mt * BM >= cnt) return;
  const int off = offsets[e];
  const int tid  = threadIdx.x;
  const int lane = tid & 63;
  const int wid  = tid >> 6;

  __shared__ u16 A_lds[2][BM * BK];   // 2 x 8 KB
  __shared__ u16 B1_lds[BN * BK];     // 4 KB
  __shared__ u16 B3_lds[BN * BK];     // 4 KB

  // A staging: issue r covers rows r*64 + wid*16 + (lane>>2); granule lane&3
  // holds global granule (lane&3)^(row&3)  (row&3 == (lane>>2)&3).
  const u16* a_src[2];
#pragma unroll
  for (int r = 0; r < 2; ++r) {
    int mg = mt * BM + r * 64 + wid * 16 + (lane >> 2);
    int mc = (mg < cnt) ? mg : (cnt - 1);
    int tok = token_list[off + mc];
    a_src[r] = Xb + (size_t)tok * HDIM + (((lane & 3) ^ ((lane >> 2) & 3)) * 8);
  }

  // B staging: thread covers col n_t, k-granule kq (8 consecutive k).
  const int n_t = tid & 63;
  const int kq  = tid >> 6;
  const float* p1 = w1 + (size_t)e * HDIM * FDIM + (size_t)(kq * 8) * FDIM + nt * BN + n_t;
  const float* p3 = w3 + (size_t)e * HDIM * FDIM + (size_t)(kq * 8) * FDIM + nt * BN + n_t;
  u16* bw1 = &B1_lds[n_t * BK + ((kq ^ (n_t & 3)) * 8)];
  u16* bw3 = &B3_lds[n_t * BK + ((kq ^ (n_t & 3)) * 8)];

  const int wm = (wid >> 1) * 64;
  const int wn = (wid & 1) * 32;

  f32x4 accg[4][2] = {};
  f32x4 accu[4][2] = {};

  float v1[8], v3[8];
  // prologue
#pragma unroll
  for (int r = 0; r < 2; ++r)
    glds16(a_src[r], &A_lds[0][r * 2048 + wid * 512]);
#pragma unroll
  for (int i = 0; i < 8; ++i) v1[i] = p1[(size_t)i * FDIM];
#pragma unroll
  for (int i = 0; i < 8; ++i) v3[i] = p3[(size_t)i * FDIM];
  p1 += (size_t)BK * FDIM;
  p3 += (size_t)BK * FDIM;

#pragma unroll 1
  for (int t = 0; t < NK1; ++t) {
    u16x8 q;
#pragma unroll
    for (int i = 0; i < 8; ++i) q[i] = f2bf(v1[i]);
    *(u16x8*)bw1 = q;
#pragma unroll
    for (int i = 0; i < 8; ++i) q[i] = f2bf(v3[i]);
    *(u16x8*)bw3 = q;
    __syncthreads();   // tile t ready (A glds drained; B written)

    if (t + 1 < NK1) {   // prefetch t+1; drained at the post-MFMA barrier
      const int ks = (t + 1) * BK;
#pragma unroll
      for (int r = 0; r < 2; ++r)
        glds16(a_src[r] + ks, &A_lds[(t + 1) & 1][r * 2048 + wid * 512]);
#pragma unroll
      for (int i = 0; i < 8; ++i) v1[i] = p1[(size_t)i * FDIM];
#pragma unroll
      for (int i = 0; i < 8; ++i) v3[i] = p3[(size_t)i * FDIM];
      p1 += (size_t)BK * FDIM;
      p3 += (size_t)BK * FDIM;
    }

    const u16* Ab = A_lds[t & 1];
    bf16x8 af[4], bg[2], bu[2];
#pragma unroll
    for (int m = 0; m < 4; ++m) {
      int R = wm + m * 16 + (lane & 15);
      af[m] = *(const bf16x8*)&Ab[R * BK + ((((lane >> 4) ^ (R & 3))) * 8)];
    }
#pragma unroll
    for (int n = 0; n < 2; ++n) {
      int R = wn + n * 16 + (lane & 15);
      bg[n] = *(const bf16x8*)&B1_lds[R * BK + ((((lane >> 4) ^ (R & 3))) * 8)];
      bu[n] = *(const bf16x8*)&B3_lds[R * BK + ((((lane >> 4) ^ (R & 3))) * 8)];
    }
#pragma unroll
    for (int m = 0; m < 4; ++m)
#pragma unroll
      for (int n = 0; n < 2; ++n) {
        accg[m][n] = __builtin_amdgcn_mfma_f32_16x16x32_bf16(af[m], bg[n], accg[m][n], 0, 0, 0);
        accu[m][n] = __builtin_amdgcn_mfma_f32_16x16x32_bf16(af[m], bu[n], accu[m][n], 0, 0, 0);
      }
    __syncthreads();
  }

  // epilogue: silu(g)*u*w.  C/D: col=lane&15, row=(lane>>4)*4+j
  const int rb = mt * BM + wm;
#pragma unroll
  for (int m = 0; m < 4; ++m) {
#pragma unroll
    for (int j = 0; j < 4; ++j) {
      int mg = rb + m * 16 + (lane >> 4) * 4 + j;
      if (mg < cnt) {
        int slot = off + mg;
        float wgt = slot_w[slot];
#pragma unroll
        for (int n = 0; n < 2; ++n) {
          float g = accg[m][n][j];
          float u = accu[m][n][j];
          float sv = g / (1.f + __expf(-g));
          act[(size_t)slot * FDIM + nt * BN + wn + n * 16 + (lane & 15)] = f2bf(sv * u * wgt);
        }
      }
    }
  }
}

// ---------------------------------------------------------------------------
// GEMM2: y[token,h] += act[slot,:] @ w2[e]  (fp32 atomics, 2 addends/elem)
// ---------------------------------------------------------------------------
__global__ __launch_bounds__(NTHR, 4)
void gemm2_kernel(const u16* __restrict__ act,
                  const float* __restrict__ w2,
                  const int* __restrict__ token_list,
                  const int* __restrict__ counts,
                  const int* __restrict__ offsets,
                  float* __restrict__ y) {
  const int bid  = blockIdx.x;
  const int orig = (bid & 7) * (GRID2 / 8) + (bid >> 3);
  const int e  = orig >> 9;           // / (NT2*MT_MAX)
  const int nt = (orig >> 4) & 31;
  const int mt = orig & 15;
  const int cnt = counts[e];
  if (mt * BM >= cnt) return;
  const int off = offsets[e];
  const int tid  = threadIdx.x;
  const int lane = tid & 63;
  const int wid  = tid >> 6;

  __shared__ u16 A_lds[2][BM * BK];
  __shared__ u16 B_lds[BN * BK];

  const u16* a_src[2];
#pragma unroll
  for (int r = 0; r < 2; ++r) {
    int mg = mt * BM + r * 64 + wid * 16 + (lane >> 2);
    int mc = (mg < cnt) ? mg : (cnt - 1);
    a_src[r] = act + (size_t)(off + mc) * FDIM + (((lane & 3) ^ ((lane >> 2) & 3)) * 8);
  }
  const int n_t = tid & 63;
  const int kq  = tid >> 6;
  const float* p2 = w2 + (size_t)e * FDIM * HDIM + (size_t)(kq * 8) * HDIM + nt * BN + n_t;
  u16* bw = &B_lds[n_t * BK + ((kq ^ (n_t & 3)) * 8)];

  const int wm = (wid >> 1) * 64;
  const int wn = (wid & 1) * 32;
  f32x4 acc[4][2] = {};

  float v[8];
#pragma unroll
  for (int r = 0; r < 2; ++r)
    glds16(a_src[r], &A_lds[0][r * 2048 + wid * 512]);
#pragma unroll
  for (int i = 0; i < 8; ++i) v[i] = p2[(size_t)i * HDIM];
  p2 += (size_t)BK * HDIM;

#pragma unroll 1
  for (int t = 0; t < NK2; ++t) {
    u16x8 q;
#pragma unroll
    for (int i = 0; i < 8; ++i) q[i] = f2bf(v[i]);
    *(u16x8*)bw = q;
    __syncthreads();

    if (t + 1 < NK2) {
      const int ks = (t + 1) * BK;
#pragma unroll
      for (int r = 0; r < 2; ++r)
        glds16(a_src[r] + ks, &A_lds[(t + 1) & 1][r * 2048 + wid * 512]);
#pragma unroll
      for (int i = 0; i < 8; ++i) v[i] = p2[(size_t)i * HDIM];
      p2 += (size_t)BK * HDIM;
    }

    const u16* Ab = A_lds[t & 1];
    bf16x8 af[4], bb[2];
#pragma unroll
    for (int m = 0; m < 4; ++m) {
      int R = wm + m * 16 + (lane & 15);
      af[m] = *(const bf16x8*)&Ab[R * BK + ((((lane >> 4) ^ (R & 3))) * 8)];
    }
#pragma unroll
    for (int n = 0; n < 2; ++n) {
      int R = wn + n * 16 + (lane & 15);
      bb[n] = *(const bf16x8*)&B_lds[R * BK + ((((lane >> 4) ^ (R & 3))) * 8)];
    }
#pragma unroll
    for (int m = 0; m < 4; ++m)
#pragma unroll
      for (int n = 0; n < 2; ++n)
        acc[m][n] = __builtin_amdgcn_mfma_f32_16x16x32_bf16(af[m], bb[n], acc[m][n], 0, 0, 0);
    __syncthreads();
  }

  const int rb = mt * BM + wm;
#pragma unroll
  for (int m = 0; m < 4; ++m) {
#pragma unroll
    for (int j = 0; j < 4; ++j) {
      int mg = rb + m * 16 + (lane >> 4) * 4 + j;
      if (mg < cnt) {
        int slot = off + mg;
        int tok = token_list[slot];
        float* yp = y + (size_t)tok * HDIM + nt * BN + wn + (lane & 15);
#pragma unroll
        for (int n = 0; n < 2; ++n)
          unsafeAtomicAdd(yp + n * 16, acc[m][n][j]);
      }
    }
  }
}

// ---------------------------------------------------------------------------
extern "C" void kernel_launch(void* const* d_in, const int* in_sizes, int n_in,
                              void* d_out, int out_size, void* d_ws, size_t ws_size,
                              hipStream_t stream) {
  (void)in_sizes; (void)n_in; (void)out_size; (void)ws_size;
  const float* hs     = (const float*)d_in[0];
  const float* logits = (const float*)d_in[1];
  const float* w1     = (const float*)d_in[2];
  const float* w3     = (const float*)d_in[3];
  const float* w2     = (const float*)d_in[4];
  float* y = (float*)d_out;

  uint8_t* ws = (uint8_t*)d_ws;
  int*   token_list = (int*)(ws);
  float* slot_w     = (float*)(ws + (16 << 10));
  int*   counts     = (int*)(ws + (32 << 10));
  int*   offsets    = (int*)(ws + (32 << 10) + 128);
  int*   cursor     = (int*)(ws + (32 << 10) + 256);
  int*   tok_e      = (int*)(ws + (33 << 10));
  float* tok_w      = (float*)(ws + (42 << 10));
  u16*   Xb         = (u16*)(ws + (64 << 10));
  u16*   act        = (u16*)(ws + (64 << 10) + (size_t)T_TOK * HDIM * 2);

  hipMemsetAsync(counts, 0, NEXP * sizeof(int), stream);
  route1_kernel<<<T_TOK / 256, 256, 0, stream>>>(logits, tok_e, tok_w, counts);
  route2_kernel<<<1, 64, 0, stream>>>(counts, offsets, cursor);
  route3_kernel<<<T_TOK / 256, 256, 0, stream>>>(tok_e, tok_w, cursor, token_list, slot_w);
  convert_x_kernel<<<(T_TOK * HDIM / 4) / 256, 256, 0, stream>>>((const float4*)hs, (ushort4*)Xb);
  hipMemsetAsync(d_out, 0, (size_t)T_TOK * HDIM * sizeof(float), stream);
  gemm1_kernel<<<GRID1, NTHR, 0, stream>>>(Xb, w1, w3, token_list, slot_w, counts, offsets, act);
  gemm2_kernel<<<GRID2, NTHR, 0, stream>>>(act, w2, token_list, counts, offsets, y);
}

// Round 4
// 185.628 us; speedup vs baseline: 1.3450x; 1.0350x over previous
//
#include <hip/hip_runtime.h>
#include <stdint.h>

#define T_TOK 2048
#define HDIM  2048
#define FDIM  1024
#define NEXP  8

#define BM   64
#define BN   64
#define BK   32
#define NTHR 256
#define MT_MAX (T_TOK / BM)      // 32
#define NT1 (FDIM / BN)          // 16
#define NT2 (HDIM / BN)          // 32
#define NK1 (HDIM / BK)          // 64
#define NK2 (FDIM / BK)          // 32
#define GRID1 (NEXP * MT_MAX * NT1)   // 4096
#define GRID2 (NEXP * MT_MAX * NT2)   // 8192

typedef unsigned short u16;
typedef __attribute__((ext_vector_type(4))) float f32x4;
typedef __attribute__((ext_vector_type(8))) short bf16x8;
typedef __attribute__((ext_vector_type(8))) unsigned short u16x8;

__device__ __forceinline__ u16 f2bf(float f) {
  uint32_t u = __float_as_uint(f);
  u += 0x7FFFu + ((u >> 16) & 1u);   // RNE
  return (u16)(u >> 16);
}

__device__ __forceinline__ void glds16(const u16* src, u16* dst) {
  __builtin_amdgcn_global_load_lds(
      (const __attribute__((address_space(1))) uint32_t*)src,
      (__attribute__((address_space(3))) uint32_t*)dst, 16, 0, 0);
}

// ---------------------------------------------------------------------------
// Routing (3 tiny kernels). Slot order within an expert is run-varying, but
// y is order-invariant: per-row GEMM math is slot-position-independent and
// each y element receives exactly 2 commutative fp32 atomic addends.
// ---------------------------------------------------------------------------
__global__ void route1_kernel(const float* __restrict__ logits,
                              int* __restrict__ tok_e, float* __restrict__ tok_w,
                              int* __restrict__ counts) {
  __shared__ int lcnt[NEXP];
  const int tid = threadIdx.x;
  const int t = blockIdx.x * 256 + tid;
  if (tid < NEXP) lcnt[tid] = 0;
  __syncthreads();
  float l[NEXP];
#pragma unroll
  for (int e = 0; e < NEXP; ++e) l[e] = logits[t * NEXP + e];
  float m = l[0];
#pragma unroll
  for (int e = 1; e < NEXP; ++e) m = fmaxf(m, l[e]);
  float p[NEXP]; float s = 0.f;
#pragma unroll
  for (int e = 0; e < NEXP; ++e) { p[e] = __expf(l[e] - m); s += p[e]; }
  float inv = 1.f / s;
  int i0 = 0; float p0 = p[0];
#pragma unroll
  for (int e = 1; e < NEXP; ++e) if (p[e] > p0) { p0 = p[e]; i0 = e; }
  int i1 = -1; float p1 = -1.f;
#pragma unroll
  for (int e = 0; e < NEXP; ++e) if (e != i0 && p[e] > p1) { p1 = p[e]; i1 = e; }
  tok_e[t] = i0 | (i1 << 8);
  tok_w[t * 2]     = p0 * inv;
  tok_w[t * 2 + 1] = p1 * inv;
  atomicAdd(&lcnt[i0], 1);
  atomicAdd(&lcnt[i1], 1);
  __syncthreads();
  if (tid < NEXP) atomicAdd(&counts[tid], lcnt[tid]);
}

__global__ void route2_kernel(const int* __restrict__ counts,
                              int* __restrict__ offsets, int* __restrict__ cursor) {
  if (threadIdx.x == 0) {
    int s = 0;
    for (int e = 0; e < NEXP; ++e) { offsets[e] = s; cursor[e] = s; s += counts[e]; }
    offsets[NEXP] = s;
  }
}

__global__ void route3_kernel(const int* __restrict__ tok_e, const float* __restrict__ tok_w,
                              int* __restrict__ cursor,
                              int* __restrict__ token_list, float* __restrict__ slot_w) {
  __shared__ int lcnt[NEXP], lbase[NEXP];
  const int tid = threadIdx.x;
  const int t = blockIdx.x * 256 + tid;
  if (tid < NEXP) lcnt[tid] = 0;
  __syncthreads();
  int ee = tok_e[t];
  int e0 = ee & 255, e1 = ee >> 8;
  int li0 = atomicAdd(&lcnt[e0], 1);
  int li1 = atomicAdd(&lcnt[e1], 1);
  __syncthreads();
  if (tid < NEXP) lbase[tid] = atomicAdd(&cursor[tid], lcnt[tid]);
  __syncthreads();
  int s0 = lbase[e0] + li0;
  int s1 = lbase[e1] + li1;
  token_list[s0] = t; slot_w[s0] = tok_w[t * 2];
  token_list[s1] = t; slot_w[s1] = tok_w[t * 2 + 1];
}

__global__ void convert_x_kernel(const float4* __restrict__ x, ushort4* __restrict__ xb) {
  int i = blockIdx.x * 256 + threadIdx.x;
  float4 v = x[i];
  ushort4 o;
  o.x = f2bf(v.x); o.y = f2bf(v.y); o.z = f2bf(v.z); o.w = f2bf(v.w);
  xb[i] = o;
}

// ---------------------------------------------------------------------------
// GEMM1: act[slot,f] = silu(x@w1)*(x@w3)*combine_w  (bf16 out)
// BM=64 BN=64 BK=32, 256 thr (2x2 waves of 32x32). TLP-first: ~4 real
// blocks/CU co-resident cover each other's load-drain stalls.
// LDS granule swizzle s(x)=(x>>1)&3 (conflict-free write AND read).
// ---------------------------------------------------------------------------
__global__ __launch_bounds__(NTHR, 4)
void gemm1_kernel(const u16* __restrict__ Xb,
                  const float* __restrict__ w1,
                  const float* __restrict__ w3,
                  const int* __restrict__ token_list,
                  const float* __restrict__ slot_w,
                  const int* __restrict__ counts,
                  const int* __restrict__ offsets,
                  u16* __restrict__ act) {
  const int bid = blockIdx.x;
  const int e  = bid >> 9;           // / (MT_MAX*NT1)
  const int mt = (bid >> 4) & 31;
  const int nt = bid & 15;           // nt fastest: B-panel sharers 16 apart
  const int cnt = counts[e];
  if (mt * BM >= cnt) return;
  const int off = offsets[e];
  const int tid  = threadIdx.x;
  const int lane = tid & 63;
  const int wid  = tid >> 6;

  __shared__ u16 A_lds[2][BM * BK];   // 2 x 4 KB
  __shared__ u16 B1_lds[BN * BK];     // 4 KB
  __shared__ u16 B3_lds[BN * BK];     // 4 KB

  // A staging: wave w stages rows [w*16, w*16+16); lane -> row w*16+(lane>>2),
  // granule lane&3. Source granule pre-swizzled by s(row)=(row>>1)&3.
  const int rr = lane >> 2;
  {
  }
  const u16* a_src;
  {
    int mg = mt * BM + wid * 16 + rr;
    int mc = (mg < cnt) ? mg : (cnt - 1);
    int tok = token_list[off + mc];
    a_src = Xb + (size_t)tok * HDIM + (((lane & 3) ^ ((rr >> 1) & 3)) * 8);
  }

  // B staging: thread covers col=tid&63, k-granule kq=tid>>6 (8 k each).
  const int colb = tid & 63;
  const int kq   = tid >> 6;
  const float* p1 = w1 + (size_t)e * HDIM * FDIM + (size_t)(kq * 8) * FDIM + nt * BN + colb;
  const float* p3 = w3 + (size_t)e * HDIM * FDIM + (size_t)(kq * 8) * FDIM + nt * BN + colb;
  u16* bw1 = &B1_lds[colb * BK + ((kq ^ ((colb >> 1) & 3)) * 8)];
  u16* bw3 = &B3_lds[colb * BK + ((kq ^ ((colb >> 1) & 3)) * 8)];

  const int wm = (wid >> 1) * 32;
  const int wn = (wid & 1) * 32;

  f32x4 accg[2][2] = {};
  f32x4 accu[2][2] = {};

  float v1[8], v3[8];
  glds16(a_src, &A_lds[0][wid * 512]);
#pragma unroll
  for (int i = 0; i < 8; ++i) v1[i] = p1[(size_t)i * FDIM];
#pragma unroll
  for (int i = 0; i < 8; ++i) v3[i] = p3[(size_t)i * FDIM];
  p1 += (size_t)BK * FDIM;
  p3 += (size_t)BK * FDIM;

#pragma unroll 1
  for (int t = 0; t < NK1; ++t) {
    u16x8 q;
#pragma unroll
    for (int i = 0; i < 8; ++i) q[i] = f2bf(v1[i]);
    *(u16x8*)bw1 = q;
#pragma unroll
    for (int i = 0; i < 8; ++i) q[i] = f2bf(v3[i]);
    *(u16x8*)bw3 = q;
    __syncthreads();   // tile t ready

    if (t + 1 < NK1) {   // prefetch t+1; drained at the post-MFMA barrier
      glds16(a_src + (t + 1) * BK, &A_lds[(t + 1) & 1][wid * 512]);
#pragma unroll
      for (int i = 0; i < 8; ++i) v1[i] = p1[(size_t)i * FDIM];
#pragma unroll
      for (int i = 0; i < 8; ++i) v3[i] = p3[(size_t)i * FDIM];
      p1 += (size_t)BK * FDIM;
      p3 += (size_t)BK * FDIM;
    }

    const u16* Ab = A_lds[t & 1];
    bf16x8 af[2], bg[2], bu[2];
#pragma unroll
    for (int m = 0; m < 2; ++m) {
      int R = wm + m * 16 + (lane & 15);
      af[m] = *(const bf16x8*)&Ab[R * BK + (((lane >> 4) ^ ((R >> 1) & 3)) * 8)];
    }
#pragma unroll
    for (int n = 0; n < 2; ++n) {
      int C = wn + n * 16 + (lane & 15);
      int pos = ((lane >> 4) ^ ((C >> 1) & 3)) * 8;
      bg[n] = *(const bf16x8*)&B1_lds[C * BK + pos];
      bu[n] = *(const bf16x8*)&B3_lds[C * BK + pos];
    }
#pragma unroll
    for (int m = 0; m < 2; ++m)
#pragma unroll
      for (int n = 0; n < 2; ++n) {
        accg[m][n] = __builtin_amdgcn_mfma_f32_16x16x32_bf16(af[m], bg[n], accg[m][n], 0, 0, 0);
        accu[m][n] = __builtin_amdgcn_mfma_f32_16x16x32_bf16(af[m], bu[n], accu[m][n], 0, 0, 0);
      }
    __syncthreads();
  }

  // epilogue: silu(g)*u*w.  C/D: col=lane&15, row=(lane>>4)*4+j
  const int rb = mt * BM + wm;
#pragma unroll
  for (int m = 0; m < 2; ++m) {
#pragma unroll
    for (int j = 0; j < 4; ++j) {
      int mg = rb + m * 16 + (lane >> 4) * 4 + j;
      if (mg < cnt) {
        int slot = off + mg;
        float wgt = slot_w[slot];
#pragma unroll
        for (int n = 0; n < 2; ++n) {
          float g = accg[m][n][j];
          float u = accu[m][n][j];
          float sv = g / (1.f + __expf(-g));
          act[(size_t)slot * FDIM + nt * BN + wn + n * 16 + (lane & 15)] = f2bf(sv * u * wgt);
        }
      }
    }
  }
}

// ---------------------------------------------------------------------------
// GEMM2: y[token,h] += act[slot,:] @ w2[e]  (fp32 atomics, 2 addends/elem)
// ---------------------------------------------------------------------------
__global__ __launch_bounds__(NTHR, 4)
void gemm2_kernel(const u16* __restrict__ act,
                  const float* __restrict__ w2,
                  const int* __restrict__ token_list,
                  const int* __restrict__ counts,
                  const int* __restrict__ offsets,
                  float* __restrict__ y) {
  const int bid = blockIdx.x;
  const int e  = bid >> 10;          // / (MT_MAX*NT2)
  const int mt = (bid >> 5) & 31;
  const int nt = bid & 31;
  const int cnt = counts[e];
  if (mt * BM >= cnt) return;
  const int off = offsets[e];
  const int tid  = threadIdx.x;
  const int lane = tid & 63;
  const int wid  = tid >> 6;

  __shared__ u16 A_lds[2][BM * BK];
  __shared__ u16 B_lds[BN * BK];

  const int rr = lane >> 2;
  const u16* a_src;
  {
    int mg = mt * BM + wid * 16 + rr;
    int mc = (mg < cnt) ? mg : (cnt - 1);
    a_src = act + (size_t)(off + mc) * FDIM + (((lane & 3) ^ ((rr >> 1) & 3)) * 8);
  }
  const int colb = tid & 63;
  const int kq   = tid >> 6;
  const float* p2 = w2 + (size_t)e * FDIM * HDIM + (size_t)(kq * 8) * HDIM + nt * BN + colb;
  u16* bw = &B_lds[colb * BK + ((kq ^ ((colb >> 1) & 3)) * 8)];

  const int wm = (wid >> 1) * 32;
  const int wn = (wid & 1) * 32;
  f32x4 acc[2][2] = {};

  float v[8];
  glds16(a_src, &A_lds[0][wid * 512]);
#pragma unroll
  for (int i = 0; i < 8; ++i) v[i] = p2[(size_t)i * HDIM];
  p2 += (size_t)BK * HDIM;

#pragma unroll 1
  for (int t = 0; t < NK2; ++t) {
    u16x8 q;
#pragma unroll
    for (int i = 0; i < 8; ++i) q[i] = f2bf(v[i]);
    *(u16x8*)bw = q;
    __syncthreads();

    if (t + 1 < NK2) {
      glds16(a_src + (t + 1) * BK, &A_lds[(t + 1) & 1][wid * 512]);
#pragma unroll
      for (int i = 0; i < 8; ++i) v[i] = p2[(size_t)i * HDIM];
      p2 += (size_t)BK * HDIM;
    }

    const u16* Ab = A_lds[t & 1];
    bf16x8 af[2], bb[2];
#pragma unroll
    for (int m = 0; m < 2; ++m) {
      int R = wm + m * 16 + (lane & 15);
      af[m] = *(const bf16x8*)&Ab[R * BK + (((lane >> 4) ^ ((R >> 1) & 3)) * 8)];
    }
#pragma unroll
    for (int n = 0; n < 2; ++n) {
      int C = wn + n * 16 + (lane & 15);
      bb[n] = *(const bf16x8*)&B_lds[C * BK + (((lane >> 4) ^ ((C >> 1) & 3)) * 8)];
    }
#pragma unroll
    for (int m = 0; m < 2; ++m)
#pragma unroll
      for (int n = 0; n < 2; ++n)
        acc[m][n] = __builtin_amdgcn_mfma_f32_16x16x32_bf16(af[m], bb[n], acc[m][n], 0, 0, 0);
    __syncthreads();
  }

  const int rb = mt * BM + wm;
#pragma unroll
  for (int m = 0; m < 2; ++m) {
#pragma unroll
    for (int j = 0; j < 4; ++j) {
      int mg = rb + m * 16 + (lane >> 4) * 4 + j;
      if (mg < cnt) {
        int slot = off + mg;
        int tok = token_list[slot];
        float* yp = y + (size_t)tok * HDIM + nt * BN + wn + (lane & 15);
#pragma unroll
        for (int n = 0; n < 2; ++n)
          unsafeAtomicAdd(yp + n * 16, acc[m][n][j]);
      }
    }
  }
}

// ---------------------------------------------------------------------------
extern "C" void kernel_launch(void* const* d_in, const int* in_sizes, int n_in,
                              void* d_out, int out_size, void* d_ws, size_t ws_size,
                              hipStream_t stream) {
  (void)in_sizes; (void)n_in; (void)out_size; (void)ws_size;
  const float* hs     = (const float*)d_in[0];
  const float* logits = (const float*)d_in[1];
  const float* w1     = (const float*)d_in[2];
  const float* w3     = (const float*)d_in[3];
  const float* w2     = (const float*)d_in[4];
  float* y = (float*)d_out;

  uint8_t* ws = (uint8_t*)d_ws;
  int*   token_list = (int*)(ws);
  float* slot_w     = (float*)(ws + (16 << 10));
  int*   counts     = (int*)(ws + (32 << 10));
  int*   offsets    = (int*)(ws + (32 << 10) + 128);
  int*   cursor     = (int*)(ws + (32 << 10) + 256);
  int*   tok_e      = (int*)(ws + (33 << 10));
  float* tok_w      = (float*)(ws + (42 << 10));
  u16*   Xb         = (u16*)(ws + (64 << 10));
  u16*   act        = (u16*)(ws + (64 << 10) + (size_t)T_TOK * HDIM * 2);

  hipMemsetAsync(counts, 0, NEXP * sizeof(int), stream);
  route1_kernel<<<T_TOK / 256, 256, 0, stream>>>(logits, tok_e, tok_w, counts);
  route2_kernel<<<1, 64, 0, stream>>>(counts, offsets, cursor);
  route3_kernel<<<T_TOK / 256, 256, 0, stream>>>(tok_e, tok_w, cursor, token_list, slot_w);
  convert_x_kernel<<<(T_TOK * HDIM / 4) / 256, 256, 0, stream>>>((const float4*)hs, (ushort4*)Xb);
  hipMemsetAsync(d_out, 0, (size_t)T_TOK * HDIM * sizeof(float), stream);
  gemm1_kernel<<<GRID1, NTHR, 0, stream>>>(Xb, w1, w3, token_list, slot_w, counts, offsets, act);
  gemm2_kernel<<<GRID2, NTHR, 0, stream>>>(act, w2, token_list, counts, offsets, y);
}